// Round 8
// baseline (707.552 us; speedup 1.0000x reference)
//
#include <hip/hip_runtime.h>
#include <hip/hip_bf16.h>
#include <stdint.h>

typedef unsigned short u16;
typedef __attribute__((ext_vector_type(8))) short short8;
typedef __attribute__((ext_vector_type(4))) float float4v;

#define NNODES 11201
#define MPAD   11264
#define EEDGES 100000
#define RREL   5
#define DDIM   512
#define XLW    2560      // RREL*DDIM
#define FRAMES 1200
#define OUTC   1712      // FRAMES + DDIM

__device__ __forceinline__ float bf2f(u16 h) {
    return __uint_as_float(((uint32_t)h) << 16);
}
__device__ __forceinline__ u16 f2bf(float f) {
    uint32_t x = __float_as_uint(f);
    x += 0x7fffu + ((x >> 16) & 1u);   // RNE
    return (u16)(x >> 16);
}
__device__ __forceinline__ float fast_tanh(float v) {
    v = fminf(fmaxf(v, -10.f), 10.f);
    float ex = __expf(2.f * v);
    return (ex - 1.f) / (ex + 1.f);
}

// ---------------- CSR build ----------------
__global__ void hist_k(const int* __restrict__ rows, int* __restrict__ counts) {
    int tid = blockIdx.x * 256 + threadIdx.x;
    if (tid >= RREL * EEDGES) return;
    int r = tid / EEDGES;
    atomicAdd(&counts[r * NNODES + rows[tid]], 1);
}

// single-pass scan: 1024 threads, 11 elems/thread; writes offs AND cursor
__global__ __launch_bounds__(1024) void scan_offsets(const int* __restrict__ counts,
                                                     int* __restrict__ offs,
                                                     int* __restrict__ cursor) {
    const int PER = 11;          // 1024*11 = 11264 >= NNODES
    int r = blockIdx.x;
    const int* c = counts + (size_t)r * NNODES;
    int* o = offs + (size_t)r * (NNODES + 1);
    int* cur = cursor + (size_t)r * NNODES;
    __shared__ int wsum[16];
    const int lane = threadIdx.x & 63, wid = threadIdx.x >> 6;
    int base = threadIdx.x * PER;
    int v[PER];
    int s = 0;
    #pragma unroll
    for (int t = 0; t < PER; ++t) {
        int idx = base + t;
        v[t] = (idx < NNODES) ? c[idx] : 0;
        s += v[t];
    }
    int incl = s;
    #pragma unroll
    for (int d = 1; d < 64; d <<= 1) {
        int t = __shfl_up(incl, d, 64);
        if (lane >= d) incl += t;
    }
    if (lane == 63) wsum[wid] = incl;
    __syncthreads();
    if (wid == 0) {
        int wv = (lane < 16) ? wsum[lane] : 0;
        #pragma unroll
        for (int d = 1; d < 16; d <<= 1) {
            int t = __shfl_up(wv, d, 64);
            if (lane >= d) wv += t;
        }
        if (lane < 16) wsum[lane] = wv;
    }
    __syncthreads();
    int run = incl - s + ((wid > 0) ? wsum[wid - 1] : 0);   // exclusive prefix
    #pragma unroll
    for (int t = 0; t < PER; ++t) {
        int idx = base + t;
        if (idx < NNODES) { o[idx] = run; cur[idx] = run; }
        run += v[t];
    }
    if (threadIdx.x == 1023) o[NNODES] = run;
}

__global__ void scatter_k(const int* __restrict__ rows, const int* __restrict__ cols,
                          const float* __restrict__ vals, int* __restrict__ cursor,
                          int* __restrict__ colS, float* __restrict__ valS) {
    int tid = blockIdx.x * 256 + threadIdx.x;
    if (tid >= RREL * EEDGES) return;
    int r = tid / EEDGES;
    int row = rows[tid];
    int pos = atomicAdd(&cursor[r * NNODES + row], 1);
    colS[(size_t)r * EEDGES + pos] = cols[tid];
    valS[(size_t)r * EEDGES + pos] = vals[tid];
}

// ------- merged prep: x assembly + tsp pad + all 6 weight transposes, one dispatch ------
#define BX_BLOCKS 5601                 // ceil(NNODES*128/256)
#define TSP_BLOCKS 256
#define TR_BASE (BX_BLOCKS + TSP_BLOCKS)
__global__ void prep_all(const float* __restrict__ frame_emb,
                         const float* __restrict__ role_emb,
                         const int* __restrict__ fe_ids,
                         const float* __restrict__ ts,
                         const float* __restrict__ w0, const float* __restrict__ w1,
                         const float* __restrict__ s1, const float* __restrict__ s2,
                         const float* __restrict__ f1, const float* __restrict__ f2,
                         u16* __restrict__ x, u16* __restrict__ tsp,
                         u16* __restrict__ w0t, u16* __restrict__ w1t,
                         u16* __restrict__ s1t, u16* __restrict__ s2t,
                         u16* __restrict__ f1t, u16* __restrict__ f2t) {
    int bid = blockIdx.x;
    if (bid < BX_BLOCKS) {
        int t = bid * 256 + threadIdx.x;
        int row = t >> 7, c4 = (t & 127) << 2;
        if (row >= NNODES) return;
        const float* src = (row < FRAMES) ? (frame_emb + (size_t)row * DDIM)
                                          : (role_emb + (size_t)fe_ids[row - FRAMES] * DDIM);
        float4 v = *(const float4*)(src + c4);
        ushort4 o = { f2bf(v.x), f2bf(v.y), f2bf(v.z), f2bf(v.w) };
        *(ushort4*)(x + (size_t)row * DDIM + c4) = o;
        return;
    }
    if (bid < TR_BASE) {
        int t = (bid - BX_BLOCKS) * 256 + threadIdx.x;   // < 65536
        int row = t >> 9, c4 = (t & 511) << 2;
        ushort4 o = {0, 0, 0, 0};
        if (row < 32) {
            float4 v = *(const float4*)(ts + (size_t)row * 2048 + c4);
            o = ushort4{ f2bf(v.x), f2bf(v.y), f2bf(v.z), f2bf(v.w) };
        }
        *(ushort4*)(tsp + (size_t)row * 2048 + c4) = o;
        return;
    }
    int b = bid - TR_BASE;
    const float* src; u16* dst;
    int cols, ldOut, bx, by;
    size_t zcol = 0;
    if (b < 1280) {
        int rel = b >> 8, rem = b & 255;
        src = w0 + (size_t)rel * 262144; dst = w0t;
        cols = 512; ldOut = XLW; zcol = (size_t)rel * 512;
        bx = rem & 15; by = rem >> 4;
    } else if (b < 2560) {
        b -= 1280;
        int rel = b >> 8, rem = b & 255;
        src = w1 + (size_t)rel * 262144; dst = w1t;
        cols = 512; ldOut = XLW; zcol = (size_t)rel * 512;
        bx = rem & 15; by = rem >> 4;
    } else if (b < 6656) {
        b -= 2560;
        src = s1; dst = s1t; cols = 2048; ldOut = 2048;
        bx = b & 63; by = b >> 6;
    } else if (b < 7680) {
        b -= 6656;
        src = s2; dst = s2t; cols = 512; ldOut = 2048;
        bx = b & 15; by = b >> 4;
    } else if (b < 7936) {
        b -= 7680;
        src = f1; dst = f1t; cols = 512; ldOut = 512;
        bx = b & 15; by = b >> 4;
    } else {
        b -= 7936;
        src = f2; dst = f2t; cols = 512; ldOut = 512;
        bx = b & 15; by = b >> 4;
    }
    __shared__ u16 tile[32][33];
    int c0 = bx * 32, r0 = by * 32;
    int tx = threadIdx.x & 31, ty = threadIdx.x >> 5;   // 256 threads
    #pragma unroll
    for (int i = 0; i < 4; ++i) {
        int rr = ty + i * 8;
        tile[rr][tx] = f2bf(src[(size_t)(r0 + rr) * cols + c0 + tx]);
    }
    __syncthreads();
    #pragma unroll
    for (int i = 0; i < 4; ++i) {
        int rr = ty + i * 8;
        dst[(size_t)(c0 + rr) * ldOut + zcol + r0 + tx] = tile[tx][rr];
    }
}

// ------- register-direct BT-GEMM: NO LDS, no barriers ------------------------------------
// MFMA fragments are loaded straight from global as b128 (fragment layout == contiguous
// 16 B per lane). Tile 128m x 64n; wave w owns m rows [w*32, w*32+32); each wave covers
// all 64 n. Grid (M/128, N/64), x = m fastest => XCD-local A reuse (gridDim.x % 8 == 0).
// EPI: 0 none, 4 tanh. FOUT: fp32 store. GUARDS: m/n store guards.
template<int EPI, bool FOUT, bool GUARDS>
__global__ __launch_bounds__(256)
void gemm_reg(const u16* __restrict__ A, const u16* __restrict__ Bt,
              void* __restrict__ Cv, int K, int lda, int ldb, int ldc,
              int mGuard, int nGuard)
{
    const int lane = threadIdx.x & 63, wave = threadIdx.x >> 6;
    const int fr = lane & 15, quad = lane >> 4;
    const int m0 = blockIdx.x * 128, n0 = blockIdx.y * 64;
    const u16* Ap = A  + (size_t)(m0 + (wave << 5) + fr) * lda + (quad << 3);
    const u16* Bp = Bt + (size_t)(n0 + fr) * ldb + (quad << 3);
    const size_t lda16 = (size_t)lda * 16;
    const size_t ldb16 = (size_t)ldb * 16;
    float4v acc[2][4] = {};

    #pragma unroll 4
    for (int k0 = 0; k0 < K; k0 += 32) {
        short8 a0 = *(const short8*)(Ap + k0);
        short8 a1 = *(const short8*)(Ap + lda16 + k0);
        short8 b0 = *(const short8*)(Bp + k0);
        short8 b1 = *(const short8*)(Bp + ldb16 + k0);
        short8 b2 = *(const short8*)(Bp + 2 * ldb16 + k0);
        short8 b3 = *(const short8*)(Bp + 3 * ldb16 + k0);
        acc[0][0] = __builtin_amdgcn_mfma_f32_16x16x32_bf16(a0, b0, acc[0][0], 0, 0, 0);
        acc[0][1] = __builtin_amdgcn_mfma_f32_16x16x32_bf16(a0, b1, acc[0][1], 0, 0, 0);
        acc[0][2] = __builtin_amdgcn_mfma_f32_16x16x32_bf16(a0, b2, acc[0][2], 0, 0, 0);
        acc[0][3] = __builtin_amdgcn_mfma_f32_16x16x32_bf16(a0, b3, acc[0][3], 0, 0, 0);
        acc[1][0] = __builtin_amdgcn_mfma_f32_16x16x32_bf16(a1, b0, acc[1][0], 0, 0, 0);
        acc[1][1] = __builtin_amdgcn_mfma_f32_16x16x32_bf16(a1, b1, acc[1][1], 0, 0, 0);
        acc[1][2] = __builtin_amdgcn_mfma_f32_16x16x32_bf16(a1, b2, acc[1][2], 0, 0, 0);
        acc[1][3] = __builtin_amdgcn_mfma_f32_16x16x32_bf16(a1, b3, acc[1][3], 0, 0, 0);
    }

    #pragma unroll
    for (int i = 0; i < 2; ++i) {
        #pragma unroll
        for (int j = 0; j < 4; ++j) {
            const int n = n0 + j * 16 + fr;
            #pragma unroll
            for (int rg = 0; rg < 4; ++rg) {
                const int m = m0 + (wave << 5) + i * 16 + (quad << 2) + rg;
                if (GUARDS && (m >= mGuard || n >= nGuard)) continue;
                float v = acc[i][j][rg];
                if (EPI == 4) v = fast_tanh(v);
                if (FOUT) ((float*)Cv)[(size_t)m * ldc + n] = v;
                else      ((u16*)Cv)[(size_t)m * ldc + n] = f2bf(v);
            }
        }
    }
}

// ------- 128x128 split-K BT-GEMM (MLP stages; small C so atomics are L2-cheap) ----------
__global__ __launch_bounds__(256)
void gemm_sk(const u16* __restrict__ A, const u16* __restrict__ Bt,
             float* __restrict__ Cf, int Kc, int lda, int ldb, int ldc)
{
    __shared__ u16 As[2][128 * 32];
    __shared__ u16 Bs[2][128 * 32];
    const int tid = threadIdx.x;
    const int wave = tid >> 6, lane = tid & 63;
    const int m0 = blockIdx.y * 128, n0 = blockIdx.x * 128;
    const int kb = blockIdx.z * Kc;
    const int srow = lane >> 2;
    const int skoff = (lane & 3) << 3;
    const int fr = lane & 15, quad = lane >> 4;
    const int wm = (wave & 1) << 6, wn = (wave >> 1) << 6;
    float4v acc[4][4] = {};

    const u16* Abase = A  + (size_t)(m0 + srow) * lda + skoff;
    const u16* Bbase = Bt + (size_t)(n0 + srow) * ldb + skoff;

    auto stage = [&](int buf, int k0) {
        #pragma unroll
        for (int i = 0; i < 2; ++i) {
            const int rb = (wave + i * 4) << 4;
            __builtin_amdgcn_global_load_lds(
                (const __attribute__((address_space(1))) unsigned int*)(Abase + (size_t)rb * lda + k0),
                (__attribute__((address_space(3))) unsigned int*)(&As[buf][rb * 32]), 16, 0, 0);
            __builtin_amdgcn_global_load_lds(
                (const __attribute__((address_space(1))) unsigned int*)(Bbase + (size_t)rb * ldb + k0),
                (__attribute__((address_space(3))) unsigned int*)(&Bs[buf][rb * 32]), 16, 0, 0);
        }
    };
    auto compute = [&](int buf) {
        short8 a[4], b[4];
        #pragma unroll
        for (int t = 0; t < 4; ++t)
            a[t] = *(const short8*)(&As[buf][((wm + t * 16 + fr) << 5) + (quad << 3)]);
        #pragma unroll
        for (int t = 0; t < 4; ++t)
            b[t] = *(const short8*)(&Bs[buf][((wn + t * 16 + fr) << 5) + (quad << 3)]);
        #pragma unroll
        for (int i = 0; i < 4; ++i)
            #pragma unroll
            for (int j = 0; j < 4; ++j)
                acc[i][j] = __builtin_amdgcn_mfma_f32_16x16x32_bf16(a[i], b[j], acc[i][j], 0, 0, 0);
    };

    stage(0, kb);
    __syncthreads();
    int cur = 0;
    for (int k0 = kb + 32; k0 < kb + Kc; k0 += 32) {
        stage(cur ^ 1, k0);
        compute(cur);
        __syncthreads();
        cur ^= 1;
    }
    compute(cur);

    #pragma unroll
    for (int i = 0; i < 4; ++i)
        #pragma unroll
        for (int j = 0; j < 4; ++j) {
            const int n = n0 + wn + j * 16 + fr;
            #pragma unroll
            for (int rg = 0; rg < 4; ++rg) {
                const int m = m0 + wm + i * 16 + (quad << 2) + rg;
                atomicAdd(&Cf[(size_t)m * ldc + n], acc[i][j][rg]);
            }
        }
}

// split-K epilogue: [bias] + act + bf16 store. ACT: 0=none, 1=relu, 3=tanh
template<int ACT, bool HASB>
__global__ void sk_ep(const float* __restrict__ Cf, const float* __restrict__ bias,
                      u16* __restrict__ outp, int Ncols, int total4) {
    int t = blockIdx.x * 256 + threadIdx.x;
    if (t >= total4) return;
    int i = t << 2;
    float4 v = *(const float4*)(Cf + i);
    if (HASB) {
        int col = i & (Ncols - 1);
        v.x += bias[col]; v.y += bias[col + 1]; v.z += bias[col + 2]; v.w += bias[col + 3];
    }
    if (ACT == 1) { v.x = fmaxf(v.x, 0.f); v.y = fmaxf(v.y, 0.f);
                    v.z = fmaxf(v.z, 0.f); v.w = fmaxf(v.w, 0.f); }
    if (ACT == 3) { v.x = fast_tanh(v.x); v.y = fast_tanh(v.y);
                    v.z = fast_tanh(v.z); v.w = fast_tanh(v.w); }
    ushort4 o = { f2bf(v.x), f2bf(v.y), f2bf(v.z), f2bf(v.w) };
    *(ushort4*)(outp + i) = o;
}

// ---------------- gather-aggregate, one wave per (node, relation) ------------------------
__device__ __forceinline__ void fma8(float* acc, uint4 u, float val) {
    acc[0] = fmaf(val, __uint_as_float(u.x << 16), acc[0]);
    acc[1] = fmaf(val, __uint_as_float(u.x & 0xffff0000u), acc[1]);
    acc[2] = fmaf(val, __uint_as_float(u.y << 16), acc[2]);
    acc[3] = fmaf(val, __uint_as_float(u.y & 0xffff0000u), acc[3]);
    acc[4] = fmaf(val, __uint_as_float(u.z << 16), acc[4]);
    acc[5] = fmaf(val, __uint_as_float(u.z & 0xffff0000u), acc[5]);
    acc[6] = fmaf(val, __uint_as_float(u.w << 16), acc[6]);
    acc[7] = fmaf(val, __uint_as_float(u.w & 0xffff0000u), acc[7]);
}

__global__ __launch_bounds__(256)
void spmm_agg(const u16* __restrict__ x, const int* __restrict__ offs,
              const int* __restrict__ colS, const float* __restrict__ valS,
              u16* __restrict__ agg)
{
    const int wave = threadIdx.x >> 6, lane = threadIdx.x & 63;
    const int n = blockIdx.x * 4 + wave;
    const int r = blockIdx.y;
    if (n >= NNODES) return;
    const u16* xr = x + (lane << 3);
    int s = offs[r * (NNODES + 1) + n];
    const int e = offs[r * (NNODES + 1) + n + 1];
    const int*   cp = colS + (size_t)r * EEDGES;
    const float* vp = valS + (size_t)r * EEDGES;
    float acc[8] = {0.f, 0.f, 0.f, 0.f, 0.f, 0.f, 0.f, 0.f};
    while (s < e) {                    // depth-8 batches, wave-uniform guards
        int m = e - s; if (m > 8) m = 8;
        int   ct[8]; float vt[8]; uint4 u[8];
        #pragma unroll
        for (int t = 0; t < 8; ++t)
            if (t < m) { ct[t] = cp[s + t]; vt[t] = vp[s + t]; }
        #pragma unroll
        for (int t = 0; t < 8; ++t)
            if (t < m) u[t] = *(const uint4*)(xr + (size_t)ct[t] * DDIM);
        #pragma unroll
        for (int t = 0; t < 8; ++t)
            if (t < m) fma8(acc, u[t], vt[t]);
        s += 8;
    }
    uint4 o;
    o.x = (uint32_t)f2bf(acc[0]) | ((uint32_t)f2bf(acc[1]) << 16);
    o.y = (uint32_t)f2bf(acc[2]) | ((uint32_t)f2bf(acc[3]) << 16);
    o.z = (uint32_t)f2bf(acc[4]) | ((uint32_t)f2bf(acc[5]) << 16);
    o.w = (uint32_t)f2bf(acc[6]) | ((uint32_t)f2bf(acc[7]) << 16);
    *(uint4*)(agg + (size_t)n * XLW + (r << 9) + (lane << 3)) = o;
}

// ---------------- frame_node gather (bf16 emb -> fp32 out) ----------------
__global__ void frame_gather(const u16* __restrict__ emb, const int* __restrict__ frame_list,
                             const int* __restrict__ gold, float* __restrict__ out) {
    int t = blockIdx.x * 256 + threadIdx.x;   // 32*64
    if (t >= 32 * 64) return;
    int b = t >> 6, lane = t & 63;
    int label = frame_list[b * 16 + gold[b]];
    const u16* src = emb + (size_t)label * DDIM + (lane << 3);
    float* dst = out + (size_t)b * OUTC + FRAMES + (lane << 3);
    float4 o0 = { bf2f(src[0]), bf2f(src[1]), bf2f(src[2]), bf2f(src[3]) };
    float4 o1 = { bf2f(src[4]), bf2f(src[5]), bf2f(src[6]), bf2f(src[7]) };
    *(float4*)(dst) = o0;
    *(float4*)(dst + 4) = o1;
}

extern "C" void kernel_launch(void* const* d_in, const int* in_sizes, int n_in,
                              void* d_out, int out_size, void* d_ws, size_t ws_size,
                              hipStream_t stream) {
    const float* target_span = (const float*)d_in[0];
    const float* frame_emb   = (const float*)d_in[1];
    const float* role_emb    = (const float*)d_in[2];
    const float* rel_W0      = (const float*)d_in[3];
    const float* rel_W1      = (const float*)d_in[4];
    const float* span_W1     = (const float*)d_in[5];
    const float* span_b1     = (const float*)d_in[6];
    const float* span_W2     = (const float*)d_in[7];
    const float* span_b2     = (const float*)d_in[8];
    const float* fp_W1       = (const float*)d_in[9];
    const float* fp_b1       = (const float*)d_in[10];
    const float* fp_W2       = (const float*)d_in[11];
    const float* fp_b2       = (const float*)d_in[12];
    const float* adj_vals    = (const float*)d_in[13];
    const int* fe_ids      = (const int*)d_in[14];
    const int* adj_rows    = (const int*)d_in[15];
    const int* adj_cols    = (const int*)d_in[16];
    const int* gold_id     = (const int*)d_in[17];
    const int* frame_list  = (const int*)d_in[18];
    float* out = (float*)d_out;

    char* ws = (char*)d_ws;
    size_t off = 0;
    auto take = [&](size_t bytes) -> char* {
        char* p = ws + off;
        off = (off + bytes + 255) & ~(size_t)255;
        return p;
    };
    u16* x      = (u16*)take((size_t)MPAD * DDIM * 2);
    u16* agg    = (u16*)take((size_t)MPAD * XLW * 2);
    u16* w0t    = (u16*)take((size_t)512 * XLW * 2);     // Wcat0^T: [512 n][2560 k]
    u16* w1t    = (u16*)take((size_t)512 * XLW * 2);
    u16* s1t    = (u16*)take((size_t)2048 * 2048 * 2);
    u16* s2t    = (u16*)take((size_t)512 * 2048 * 2);
    u16* f1t    = (u16*)take((size_t)512 * 512 * 2);
    u16* f2t    = (u16*)take((size_t)512 * 512 * 2);
    // counts + CfAll contiguous -> single memset covers both
    int* counts = (int*)take((size_t)RREL * NNODES * 4);
    float* CfAll = (float*)take((size_t)(128 * 2048 + 3 * 128 * 512) * 4);
    int* offs   = (int*)take((size_t)RREL * (NNODES + 1) * 4);
    int* cursor = (int*)take((size_t)RREL * NNODES * 4);
    int* colS   = (int*)take((size_t)RREL * EEDGES * 4);
    float* valS = (float*)take((size_t)RREL * EEDGES * 4);
    u16* tsp    = (u16*)take((size_t)128 * 2048 * 2);
    u16* h1     = (u16*)take((size_t)128 * 2048 * 2);
    u16* tn     = (u16*)take((size_t)128 * 512 * 2);
    u16* h2     = (u16*)take((size_t)128 * 512 * 2);
    u16* Qb     = (u16*)take((size_t)128 * 512 * 2);
    float* Cf1 = CfAll;
    float* Cf2 = Cf1 + 128 * 2048;
    float* Cf3 = Cf2 + 128 * 512;
    float* Cf4 = Cf3 + 128 * 512;

    size_t zlen = (char*)(CfAll + 128 * 2048 + 3 * 128 * 512) - (char*)counts;
    hipMemsetAsync(counts, 0, zlen, stream);

    // CSR build (shared by both layers)
    hist_k<<<(RREL * EEDGES + 255) / 256, 256, 0, stream>>>(adj_rows, counts);
    scan_offsets<<<RREL, 1024, 0, stream>>>(counts, offs, cursor);
    scatter_k<<<(RREL * EEDGES + 255) / 256, 256, 0, stream>>>(adj_rows, adj_cols, adj_vals,
                                                               cursor, colS, valS);
    // merged input/weight prep
    prep_all<<<TR_BASE + 8192, 256, 0, stream>>>(frame_emb, role_emb, fe_ids, target_span,
                                                 rel_W0, rel_W1, span_W1, span_W2, fp_W1, fp_W2,
                                                 x, tsp, w0t, w1t, s1t, s2t, f1t, f2t);

    // relGCN layer 1: gather-agg (per node,rel) -> register-direct GEMM, fused tanh
    spmm_agg<<<dim3((NNODES + 3) / 4, RREL), 256, 0, stream>>>(x, offs, colS, valS, agg);
    gemm_reg<4, false, true><<<dim3(MPAD / 128, 8), 256, 0, stream>>>(
        agg, w0t, x, XLW, XLW, XLW, 512, NNODES, 512);
    // relGCN layer 2
    spmm_agg<<<dim3((NNODES + 3) / 4, RREL), 256, 0, stream>>>(x, offs, colS, valS, agg);
    gemm_reg<4, false, true><<<dim3(MPAD / 128, 8), 256, 0, stream>>>(
        agg, w1t, x, XLW, XLW, XLW, 512, NNODES, 512);

    // span MLP chain via split-K (small C, atomics cheap) + epilogues
    gemm_sk<<<dim3(16, 1, 8), 256, 0, stream>>>(tsp, s1t, Cf1, 256, 2048, 2048, 2048);
    sk_ep<1, true><<<(128 * 2048 / 4 + 255) / 256, 256, 0, stream>>>(Cf1, span_b1, h1, 2048, 128 * 2048 / 4);
    gemm_sk<<<dim3(4, 1, 8), 256, 0, stream>>>(h1, s2t, Cf2, 256, 2048, 2048, 512);
    sk_ep<0, true><<<(128 * 512 / 4 + 255) / 256, 256, 0, stream>>>(Cf2, span_b2, tn, 512, 128 * 512 / 4);
    gemm_sk<<<dim3(4, 1, 4), 256, 0, stream>>>(tn, f1t, Cf3, 128, 512, 512, 512);
    sk_ep<1, true><<<(128 * 512 / 4 + 255) / 256, 256, 0, stream>>>(Cf3, fp_b1, h2, 512, 128 * 512 / 4);
    gemm_sk<<<dim3(4, 1, 4), 256, 0, stream>>>(h2, f2t, Cf4, 128, 512, 512, 512);
    sk_ep<3, true><<<(128 * 512 / 4 + 255) / 256, 256, 0, stream>>>(Cf4, fp_b2, Qb, 512, 128 * 512 / 4);

    // pred_frame_weight = Q @ emb^T: direct fp32 store into out[:, :1200] (m<32, n<1200)
    gemm_reg<0, true, true><<<dim3(1, 19), 256, 0, stream>>>(
        Qb, x, out, 512, 512, 512, OUTC, 32, FRAMES);
    // frame_node gather; writes out[:, 1200:1712] as fp32
    frame_gather<<<8, 256, 0, stream>>>(x, frame_list, gold_id, out);
}

// Round 9
// 457.010 us; speedup vs baseline: 1.5482x; 1.5482x over previous
//
#include <hip/hip_runtime.h>
#include <hip/hip_bf16.h>
#include <stdint.h>

typedef unsigned short u16;
typedef __attribute__((ext_vector_type(8))) short short8;
typedef __attribute__((ext_vector_type(4))) float float4v;

#define NNODES 11201
#define MPAD   11264
#define EEDGES 100000
#define RREL   5
#define DDIM   512
#define XLW    2560      // RREL*DDIM
#define FRAMES 1200
#define OUTC   1712      // FRAMES + DDIM

#define AS1 __attribute__((address_space(1)))
#define AS3 __attribute__((address_space(3)))

__device__ __forceinline__ float bf2f(u16 h) {
    return __uint_as_float(((uint32_t)h) << 16);
}
__device__ __forceinline__ u16 f2bf(float f) {
    uint32_t x = __float_as_uint(f);
    x += 0x7fffu + ((x >> 16) & 1u);   // RNE
    return (u16)(x >> 16);
}
__device__ __forceinline__ float fast_tanh(float v) {
    v = fminf(fmaxf(v, -10.f), 10.f);
    float ex = __expf(2.f * v);
    return (ex - 1.f) / (ex + 1.f);
}
__device__ __forceinline__ void gl_lds(const u16* g, u16* l) {
    __builtin_amdgcn_global_load_lds((const AS1 unsigned int*)g, (AS3 unsigned int*)l, 16, 0, 0);
}

// ---------------- single-pass scan: writes offs AND cursor ----------------
__global__ __launch_bounds__(1024) void scan_offsets(const int* __restrict__ counts,
                                                     int* __restrict__ offs,
                                                     int* __restrict__ cursor) {
    const int PER = 11;          // 1024*11 = 11264 >= NNODES
    int r = blockIdx.x;
    const int* c = counts + (size_t)r * NNODES;
    int* o = offs + (size_t)r * (NNODES + 1);
    int* cur = cursor + (size_t)r * NNODES;
    __shared__ int wsum[16];
    const int lane = threadIdx.x & 63, wid = threadIdx.x >> 6;
    int base = threadIdx.x * PER;
    int v[PER];
    int s = 0;
    #pragma unroll
    for (int t = 0; t < PER; ++t) {
        int idx = base + t;
        v[t] = (idx < NNODES) ? c[idx] : 0;
        s += v[t];
    }
    int incl = s;
    #pragma unroll
    for (int d = 1; d < 64; d <<= 1) {
        int t = __shfl_up(incl, d, 64);
        if (lane >= d) incl += t;
    }
    if (lane == 63) wsum[wid] = incl;
    __syncthreads();
    if (wid == 0) {
        int wv = (lane < 16) ? wsum[lane] : 0;
        #pragma unroll
        for (int d = 1; d < 16; d <<= 1) {
            int t = __shfl_up(wv, d, 64);
            if (lane >= d) wv += t;
        }
        if (lane < 16) wsum[lane] = wv;
    }
    __syncthreads();
    int run = incl - s + ((wid > 0) ? wsum[wid - 1] : 0);   // exclusive prefix
    #pragma unroll
    for (int t = 0; t < PER; ++t) {
        int idx = base + t;
        if (idx < NNODES) { o[idx] = run; cur[idx] = run; }
        run += v[t];
    }
    if (threadIdx.x == 1023) o[NNODES] = run;
}

__global__ void scatter_k(const int* __restrict__ rows, const int* __restrict__ cols,
                          const float* __restrict__ vals, int* __restrict__ cursor,
                          int* __restrict__ colS, float* __restrict__ valS) {
    int tid = blockIdx.x * 256 + threadIdx.x;
    if (tid >= RREL * EEDGES) return;
    int r = tid / EEDGES;
    int row = rows[tid];
    int pos = atomicAdd(&cursor[r * NNODES + row], 1);
    colS[(size_t)r * EEDGES + pos] = cols[tid];
    valS[(size_t)r * EEDGES + pos] = vals[tid];
}

// ------- merged prep: x assembly + tsp pad + 6 weight transposes + edge histogram -------
#define BX_BLOCKS 5601                 // ceil(NNODES*128/256)
#define TSP_BLOCKS 256
#define TR_BASE (BX_BLOCKS + TSP_BLOCKS)          // 5857
#define HIST_BASE (TR_BASE + 8192)                // 14049
#define HIST_BLKS 1954                            // ceil(500000/256)
__global__ void prep_hist(const float* __restrict__ frame_emb,
                          const float* __restrict__ role_emb,
                          const int* __restrict__ fe_ids,
                          const float* __restrict__ ts,
                          const float* __restrict__ w0, const float* __restrict__ w1,
                          const float* __restrict__ s1, const float* __restrict__ s2,
                          const float* __restrict__ f1, const float* __restrict__ f2,
                          u16* __restrict__ x, u16* __restrict__ tsp,
                          u16* __restrict__ w0t, u16* __restrict__ w1t,
                          u16* __restrict__ s1t, u16* __restrict__ s2t,
                          u16* __restrict__ f1t, u16* __restrict__ f2t,
                          const int* __restrict__ adj_rows, int* __restrict__ counts) {
    int bid = blockIdx.x;
    if (bid >= HIST_BASE) {
        int t = (bid - HIST_BASE) * 256 + threadIdx.x;
        if (t < RREL * EEDGES) {
            int r = t / EEDGES;
            atomicAdd(&counts[r * NNODES + adj_rows[t]], 1);
        }
        return;
    }
    if (bid < BX_BLOCKS) {
        int t = bid * 256 + threadIdx.x;
        int row = t >> 7, c4 = (t & 127) << 2;
        if (row >= NNODES) return;
        const float* src = (row < FRAMES) ? (frame_emb + (size_t)row * DDIM)
                                          : (role_emb + (size_t)fe_ids[row - FRAMES] * DDIM);
        float4 v = *(const float4*)(src + c4);
        ushort4 o = { f2bf(v.x), f2bf(v.y), f2bf(v.z), f2bf(v.w) };
        *(ushort4*)(x + (size_t)row * DDIM + c4) = o;
        return;
    }
    if (bid < TR_BASE) {
        int t = (bid - BX_BLOCKS) * 256 + threadIdx.x;   // < 65536
        int row = t >> 9, c4 = (t & 511) << 2;
        ushort4 o = {0, 0, 0, 0};
        if (row < 32) {
            float4 v = *(const float4*)(ts + (size_t)row * 2048 + c4);
            o = ushort4{ f2bf(v.x), f2bf(v.y), f2bf(v.z), f2bf(v.w) };
        }
        *(ushort4*)(tsp + (size_t)row * 2048 + c4) = o;
        return;
    }
    int b = bid - TR_BASE;
    const float* src; u16* dst;
    int cols, ldOut, bx, by;
    size_t zcol = 0;
    if (b < 1280) {
        int rel = b >> 8, rem = b & 255;
        src = w0 + (size_t)rel * 262144; dst = w0t;
        cols = 512; ldOut = XLW; zcol = (size_t)rel * 512;
        bx = rem & 15; by = rem >> 4;
    } else if (b < 2560) {
        b -= 1280;
        int rel = b >> 8, rem = b & 255;
        src = w1 + (size_t)rel * 262144; dst = w1t;
        cols = 512; ldOut = XLW; zcol = (size_t)rel * 512;
        bx = rem & 15; by = rem >> 4;
    } else if (b < 6656) {
        b -= 2560;
        src = s1; dst = s1t; cols = 2048; ldOut = 2048;
        bx = b & 63; by = b >> 6;
    } else if (b < 7680) {
        b -= 6656;
        src = s2; dst = s2t; cols = 512; ldOut = 2048;
        bx = b & 15; by = b >> 4;
    } else if (b < 7936) {
        b -= 7680;
        src = f1; dst = f1t; cols = 512; ldOut = 512;
        bx = b & 15; by = b >> 4;
    } else {
        b -= 7936;
        src = f2; dst = f2t; cols = 512; ldOut = 512;
        bx = b & 15; by = b >> 4;
    }
    __shared__ u16 tile[32][33];
    int c0 = bx * 32, r0 = by * 32;
    int tx = threadIdx.x & 31, ty = threadIdx.x >> 5;   // 256 threads
    #pragma unroll
    for (int i = 0; i < 4; ++i) {
        int rr = ty + i * 8;
        tile[rr][tx] = f2bf(src[(size_t)(r0 + rr) * cols + c0 + tx]);
    }
    __syncthreads();
    #pragma unroll
    for (int i = 0; i < 4; ++i) {
        int rr = ty + i * 8;
        dst[(size_t)(c0 + rr) * ldOut + zcol + r0 + tx] = tile[tx][rr];
    }
}

// ------- MLP stage: 64x64-tile dbuf GEMM, fused bias+act, M=128 (2 m-tiles) -------------
// act: 0 none, 1 relu, 2 tanh. lds needs 8192 u16 (16 KB).
__device__ __forceinline__ void mlp_gemm(int bid, u16* lds,
    const u16* __restrict__ A, const u16* __restrict__ Bt, u16* __restrict__ C,
    const float* __restrict__ bias, int K, int lda, int ldb, int ldc, int act)
{
    const int tid = threadIdx.x;
    const int wave = tid >> 6, lane = tid & 63;
    const int fr = lane & 15, quad = lane >> 4;
    const int m0 = (bid & 1) << 6, n0 = (bid >> 1) << 6;
    const int srow = tid >> 2, sk = (tid & 3) << 3;       // srow 0..63
    const u16* Ab = A + (size_t)(m0 + srow) * lda + sk;
    const u16* Bb = Bt + (size_t)(n0 + srow) * ldb + sk;
    const int lo = srow * 32 + sk;
    float4v acc[4] = {};

    auto stage = [&](int b, int k0) {
        gl_lds(Ab + k0, lds + b * 4096 + lo);
        gl_lds(Bb + k0, lds + b * 4096 + 2048 + lo);
    };
    auto comp = [&](int b) {
        const u16* As = lds + b * 4096;
        const u16* Bs = As + 2048;
        short8 bb = *(const short8*)(Bs + (((wave << 4) + fr) << 5) + (quad << 3));
        #pragma unroll
        for (int t = 0; t < 4; ++t) {
            short8 aa = *(const short8*)(As + ((t * 16 + fr) << 5) + (quad << 3));
            acc[t] = __builtin_amdgcn_mfma_f32_16x16x32_bf16(aa, bb, acc[t], 0, 0, 0);
        }
    };
    stage(0, 0);
    __syncthreads();
    int buf = 0;
    for (int k0 = 32; k0 < K; k0 += 32) {
        stage(buf ^ 1, k0);
        comp(buf);
        __syncthreads();
        buf ^= 1;
    }
    comp(buf);

    const int n = n0 + (wave << 4) + fr;
    float bv = bias[n];
    #pragma unroll
    for (int t = 0; t < 4; ++t)
        #pragma unroll
        for (int rg = 0; rg < 4; ++rg) {
            int m = m0 + t * 16 + (quad << 2) + rg;
            float v = acc[t][rg] + bv;
            if (act == 1) v = fmaxf(v, 0.f);
            if (act == 2) v = fast_tanh(v);
            C[(size_t)m * ldc + n] = f2bf(v);
        }
}

// ------- carrier 1: spmm (gather-aggregate) + piggybacked MLP stage ---------------------
#define SPMM_BLKS 14005          // 2801 * 5
__device__ __forceinline__ void fma8(float* acc, uint4 u, float val) {
    acc[0] = fmaf(val, __uint_as_float(u.x << 16), acc[0]);
    acc[1] = fmaf(val, __uint_as_float(u.x & 0xffff0000u), acc[1]);
    acc[2] = fmaf(val, __uint_as_float(u.y << 16), acc[2]);
    acc[3] = fmaf(val, __uint_as_float(u.y & 0xffff0000u), acc[3]);
    acc[4] = fmaf(val, __uint_as_float(u.z << 16), acc[4]);
    acc[5] = fmaf(val, __uint_as_float(u.z & 0xffff0000u), acc[5]);
    acc[6] = fmaf(val, __uint_as_float(u.w << 16), acc[6]);
    acc[7] = fmaf(val, __uint_as_float(u.w & 0xffff0000u), acc[7]);
}

__global__ __launch_bounds__(256)
void spmm_mlp(const u16* __restrict__ x, const int* __restrict__ offs,
              const int* __restrict__ colS, const float* __restrict__ valS,
              u16* __restrict__ agg,
              const u16* __restrict__ mA, const u16* __restrict__ mBt,
              u16* __restrict__ mC, const float* __restrict__ mBias,
              int mK, int mLda, int mLdb, int mLdc, int mAct)
{
    __shared__ u16 lds[8192];    // 16 KB, used by mlp branch only
    const int bid = blockIdx.x;
    if (bid >= SPMM_BLKS) {
        mlp_gemm(bid - SPMM_BLKS, lds, mA, mBt, mC, mBias, mK, mLda, mLdb, mLdc, mAct);
        return;
    }
    const int wave = threadIdx.x >> 6, lane = threadIdx.x & 63;
    const int r = bid / 2801;
    const int n = (bid - r * 2801) * 4 + wave;
    if (n >= NNODES) return;
    const u16* xr = x + (lane << 3);
    int s = offs[r * (NNODES + 1) + n];
    const int e = offs[r * (NNODES + 1) + n + 1];
    const int*   cp = colS + (size_t)r * EEDGES;
    const float* vp = valS + (size_t)r * EEDGES;
    float acc[8] = {0.f, 0.f, 0.f, 0.f, 0.f, 0.f, 0.f, 0.f};
    while (s < e) {                    // depth-8 batches, wave-uniform guards
        int m = e - s; if (m > 8) m = 8;
        int   ct[8]; float vt[8]; uint4 u[8];
        #pragma unroll
        for (int t = 0; t < 8; ++t)
            if (t < m) { ct[t] = cp[s + t]; vt[t] = vp[s + t]; }
        #pragma unroll
        for (int t = 0; t < 8; ++t)
            if (t < m) u[t] = *(const uint4*)(xr + (size_t)ct[t] * DDIM);
        #pragma unroll
        for (int t = 0; t < 8; ++t)
            if (t < m) fma8(acc, u[t], vt[t]);
        s += 8;
    }
    uint4 o;
    o.x = (uint32_t)f2bf(acc[0]) | ((uint32_t)f2bf(acc[1]) << 16);
    o.y = (uint32_t)f2bf(acc[2]) | ((uint32_t)f2bf(acc[3]) << 16);
    o.z = (uint32_t)f2bf(acc[4]) | ((uint32_t)f2bf(acc[5]) << 16);
    o.w = (uint32_t)f2bf(acc[6]) | ((uint32_t)f2bf(acc[7]) << 16);
    *(uint4*)(agg + (size_t)n * XLW + (r << 9) + (lane << 3)) = o;
}

// ------- carrier 2: main relGCN GEMM (128x64 tile, BK=64, dbuf) + MLP stage -------------
// grid: 704 gemm blocks (bm = bid%88 -> XCD = bid%8 stable, all n of one m same XCD)
#define GBLK 704
__global__ __launch_bounds__(256)
void gemm_mlp(const u16* __restrict__ A, const u16* __restrict__ Bt,
              u16* __restrict__ C, int mGuard,
              const u16* __restrict__ mA, const u16* __restrict__ mBt,
              u16* __restrict__ mC, const float* __restrict__ mBias,
              int mK, int mLda, int mLdb, int mLdc, int mAct)
{
    __shared__ u16 lds[2][12288];   // per buf: A 128x64 (8192) | B 64x64 (4096); 48 KB
    const int bid = blockIdx.x;
    const int tid = threadIdx.x;
    if (bid >= GBLK) {
        mlp_gemm(bid - GBLK, &lds[0][0], mA, mBt, mC, mBias, mK, mLda, mLdb, mLdc, mAct);
        return;
    }
    const int wave = tid >> 6, lane = tid & 63;
    const int fr = lane & 15, quad = lane >> 4;
    const int bm = bid % 88, bn = bid / 88;
    const int m0 = bm << 7, n0 = bn << 6;
    const int srow = tid >> 3, sk = (tid & 7) << 3;   // srow 0..31, sk 0..56 (u16)
    const u16* Ab = A + (size_t)(m0 + srow) * XLW + sk;
    const u16* Bb = Bt + (size_t)(n0 + srow) * XLW + sk;
    const int wm = (wave & 1) << 6, wn = (wave >> 1) << 5;
    const int lo = (srow << 6) + sk;
    float4v acc[4][2] = {};

    auto stage = [&](int b, int k0) {
        u16* As = &lds[b][0];
        u16* Bs = &lds[b][8192];
        #pragma unroll
        for (int c = 0; c < 4; ++c)
            gl_lds(Ab + (size_t)(c * 32) * XLW + k0, As + c * 2048 + lo);
        #pragma unroll
        for (int c = 0; c < 2; ++c)
            gl_lds(Bb + (size_t)(c * 32) * XLW + k0, Bs + c * 2048 + lo);
    };
    auto comp = [&](int b) {
        const u16* As = &lds[b][0];
        const u16* Bs = &lds[b][8192];
        #pragma unroll
        for (int s = 0; s < 2; ++s) {
            short8 a[4], bb[2];
            #pragma unroll
            for (int t = 0; t < 4; ++t)
                a[t] = *(const short8*)(As + ((wm + t * 16 + fr) << 6) + (s << 5) + (quad << 3));
            #pragma unroll
            for (int t = 0; t < 2; ++t)
                bb[t] = *(const short8*)(Bs + ((wn + t * 16 + fr) << 6) + (s << 5) + (quad << 3));
            #pragma unroll
            for (int i = 0; i < 4; ++i)
                #pragma unroll
                for (int j = 0; j < 2; ++j)
                    acc[i][j] = __builtin_amdgcn_mfma_f32_16x16x32_bf16(a[i], bb[j], acc[i][j], 0, 0, 0);
        }
    };

    stage(0, 0);
    __syncthreads();
    int buf = 0;
    for (int k0 = 64; k0 < XLW; k0 += 64) {
        stage(buf ^ 1, k0);
        comp(buf);
        __syncthreads();
        buf ^= 1;
    }
    comp(buf);

    #pragma unroll
    for (int i = 0; i < 4; ++i)
        #pragma unroll
        for (int j = 0; j < 2; ++j) {
            const int n = n0 + wn + j * 16 + fr;
            #pragma unroll
            for (int rg = 0; rg < 4; ++rg) {
                const int m = m0 + wm + i * 16 + (quad << 2) + rg;
                if (m < mGuard)
                    C[(size_t)m * 512 + n] = f2bf(fast_tanh(acc[i][j][rg]));
            }
        }
}

// ------- pred_frame_weight (Q @ emb^T, fp32 store w/ guards) + frame_gather -------------
__global__ __launch_bounds__(256)
void pred_fg(const u16* __restrict__ Q, const u16* __restrict__ E,
             float* __restrict__ out,
             const int* __restrict__ frame_list, const int* __restrict__ gold)
{
    __shared__ u16 lds[8192];    // 16 KB
    const int bid = blockIdx.x;
    const int tid = threadIdx.x;
    if (bid >= 19) {
        int t = (bid - 19) * 256 + tid;
        if (t >= 32 * 64) return;
        int b = t >> 6, lane = t & 63;
        int label = frame_list[b * 16 + gold[b]];
        const u16* src = E + (size_t)label * DDIM + (lane << 3);
        float* dst = out + (size_t)b * OUTC + FRAMES + (lane << 3);
        float4 o0 = { bf2f(src[0]), bf2f(src[1]), bf2f(src[2]), bf2f(src[3]) };
        float4 o1 = { bf2f(src[4]), bf2f(src[5]), bf2f(src[6]), bf2f(src[7]) };
        *(float4*)(dst) = o0;
        *(float4*)(dst + 4) = o1;
        return;
    }
    // 64x64 tile, m0 = 0 (M=32), n0 = bid*64, K = 512
    const int wave = tid >> 6, lane = tid & 63;
    const int fr = lane & 15, quad = lane >> 4;
    const int n0 = bid << 6;
    const int srow = tid >> 2, sk = (tid & 3) << 3;
    const u16* Ab = Q + (size_t)srow * 512 + sk;
    const u16* Bb = E + (size_t)(n0 + srow) * 512 + sk;
    const int lo = (srow << 5) + sk;
    float4v acc[4] = {};
    auto stage = [&](int b, int k0) {
        gl_lds(Ab + k0, lds + b * 4096 + lo);
        gl_lds(Bb + k0, lds + b * 4096 + 2048 + lo);
    };
    auto comp = [&](int b) {
        const u16* As = lds + b * 4096;
        const u16* Bs = As + 2048;
        short8 bb = *(const short8*)(Bs + (((wave << 4) + fr) << 5) + (quad << 3));
        #pragma unroll
        for (int t = 0; t < 4; ++t) {
            short8 aa = *(const short8*)(As + ((t * 16 + fr) << 5) + (quad << 3));
            acc[t] = __builtin_amdgcn_mfma_f32_16x16x32_bf16(aa, bb, acc[t], 0, 0, 0);
        }
    };
    stage(0, 0);
    __syncthreads();
    int buf = 0;
    for (int k0 = 32; k0 < 512; k0 += 32) {
        stage(buf ^ 1, k0);
        comp(buf);
        __syncthreads();
        buf ^= 1;
    }
    comp(buf);
    const int n = n0 + (wave << 4) + fr;
    if (n >= FRAMES) return;
    #pragma unroll
    for (int t = 0; t < 4; ++t)
        #pragma unroll
        for (int rg = 0; rg < 4; ++rg) {
            int m = t * 16 + (quad << 2) + rg;
            if (m < 32)
                out[(size_t)m * OUTC + n] = acc[t][rg];
        }
}

extern "C" void kernel_launch(void* const* d_in, const int* in_sizes, int n_in,
                              void* d_out, int out_size, void* d_ws, size_t ws_size,
                              hipStream_t stream) {
    const float* target_span = (const float*)d_in[0];
    const float* frame_emb   = (const float*)d_in[1];
    const float* role_emb    = (const float*)d_in[2];
    const float* rel_W0      = (const float*)d_in[3];
    const float* rel_W1      = (const float*)d_in[4];
    const float* span_W1     = (const float*)d_in[5];
    const float* span_b1     = (const float*)d_in[6];
    const float* span_W2     = (const float*)d_in[7];
    const float* span_b2     = (const float*)d_in[8];
    const float* fp_W1       = (const float*)d_in[9];
    const float* fp_b1       = (const float*)d_in[10];
    const float* fp_W2       = (const float*)d_in[11];
    const float* fp_b2       = (const float*)d_in[12];
    const float* adj_vals    = (const float*)d_in[13];
    const int* fe_ids      = (const int*)d_in[14];
    const int* adj_rows    = (const int*)d_in[15];
    const int* adj_cols    = (const int*)d_in[16];
    const int* gold_id     = (const int*)d_in[17];
    const int* frame_list  = (const int*)d_in[18];
    float* out = (float*)d_out;

    char* ws = (char*)d_ws;
    size_t off = 0;
    auto take = [&](size_t bytes) -> char* {
        char* p = ws + off;
        off = (off + bytes + 255) & ~(size_t)255;
        return p;
    };
    u16* x      = (u16*)take((size_t)MPAD * DDIM * 2);
    u16* agg    = (u16*)take((size_t)MPAD * XLW * 2);
    u16* w0t    = (u16*)take((size_t)512 * XLW * 2);     // Wcat0^T: [512 n][2560 k]
    u16* w1t    = (u16*)take((size_t)512 * XLW * 2);
    u16* s1t    = (u16*)take((size_t)2048 * 2048 * 2);
    u16* s2t    = (u16*)take((size_t)512 * 2048 * 2);
    u16* f1t    = (u16*)take((size_t)512 * 512 * 2);
    u16* f2t    = (u16*)take((size_t)512 * 512 * 2);
    int* counts = (int*)take((size_t)RREL * NNODES * 4);
    int* offs   = (int*)take((size_t)RREL * (NNODES + 1) * 4);
    int* cursor = (int*)take((size_t)RREL * NNODES * 4);
    int* colS   = (int*)take((size_t)RREL * EEDGES * 4);
    float* valS = (float*)take((size_t)RREL * EEDGES * 4);
    u16* tsp    = (u16*)take((size_t)128 * 2048 * 2);
    u16* h1     = (u16*)take((size_t)128 * 2048 * 2);
    u16* tn     = (u16*)take((size_t)128 * 512 * 2);
    u16* h2     = (u16*)take((size_t)128 * 512 * 2);
    u16* Qb     = (u16*)take((size_t)128 * 512 * 2);

    hipMemsetAsync(counts, 0, (size_t)RREL * NNODES * 4, stream);

    // 1: all input prep + edge histogram
    prep_hist<<<HIST_BASE + HIST_BLKS, 256, 0, stream>>>(
        frame_emb, role_emb, fe_ids, target_span,
        rel_W0, rel_W1, span_W1, span_W2, fp_W1, fp_W2,
        x, tsp, w0t, w1t, s1t, s2t, f1t, f2t, adj_rows, counts);
    // 2: CSR offsets + cursor
    scan_offsets<<<RREL, 1024, 0, stream>>>(counts, offs, cursor);
    // 3: CSR scatter
    scatter_k<<<(RREL * EEDGES + 255) / 256, 256, 0, stream>>>(adj_rows, adj_cols, adj_vals,
                                                               cursor, colS, valS);
    // 4: spmm layer1 + MLP stage1 (tsp @ s1t + b1, relu -> h1), 64 mlp blocks
    spmm_mlp<<<SPMM_BLKS + 64, 256, 0, stream>>>(x, offs, colS, valS, agg,
                                                 tsp, s1t, h1, span_b1, 2048, 2048, 2048, 2048, 1);
    // 5: relGCN gemm1 (tanh -> x) + MLP stage2 (h1 @ s2t + b2 -> tn), 16 mlp blocks
    gemm_mlp<<<GBLK + 16, 256, 0, stream>>>(agg, w0t, x, NNODES,
                                            h1, s2t, tn, span_b2, 2048, 2048, 2048, 512, 0);
    // 6: spmm layer2 + MLP stage3 (tn @ f1t + b1, relu -> h2)
    spmm_mlp<<<SPMM_BLKS + 16, 256, 0, stream>>>(x, offs, colS, valS, agg,
                                                 tn, f1t, h2, fp_b1, 512, 512, 512, 512, 1);
    // 7: relGCN gemm2 (tanh -> x) + MLP stage4 (h2 @ f2t + b2, tanh -> Qb)
    gemm_mlp<<<GBLK + 16, 256, 0, stream>>>(agg, w1t, x, NNODES,
                                            h2, f2t, Qb, fp_b2, 512, 512, 512, 512, 2);
    // 8: pred_frame_weight (fp32 into out[:, :1200]) + frame_node gather (out[:, 1200:])
    pred_fg<<<19 + 8, 256, 0, stream>>>(Qb, x, out, frame_list, gold_id);
}